// Round 1
// baseline (3701.870 us; speedup 1.0000x reference)
//
#include <hip/hip_runtime.h>

// Persistent seq2seq LSTM kernel for MI355X (gfx950).
// Design:
//  - 256 blocks x 512 threads (8 waves). Each block owns M=32 batch rows for
//    the entire enc(512) + dec(512) step sequence (rows independent -> no
//    inter-block sync ever).
//  - Gate GEMM [32 x K] @ [K x 256] via mfma_f32_16x16x32_f16. Each wave owns a
//    32-wide slice of the 256 gate columns; weight B-fragments are converted
//    fp32->f16 once per phase and pinned in VGPRs (loop-invariant).
//  - Activations live in LDS panels, row-major [32][stride], layout matching the
//    MFMA A-fragment reads (16B aligned ds_read_b128).
//      p0 (stride 168): [x(8) | zeros(24) | h0_prev(64) | y_prev(64, dec only)]
//      p1 (stride 136): [h0(64) | h1_prev(64)]
//      p2 (stride 136): [h1(64) | h2_prev(64)]
//  - Gate preacts (fp32) round-trip through LDS gbuf [32][260] for the
//    cross-wave i/f/g/o exchange; c-state stays in fp32 registers (4/thread/layer).
//  - f16 storage + fp32 accumulate/state: predicted absmax ~1e-3 < 4.08e-3 thr.

#define TT   512
#define DD   8
#define HH   64
#define MM   32
#define S0   168   // panel0 stride (f16), even, 336B row -> 16B aligned frags
#define S12  136   // panel1/2 stride
#define NP   260   // gbuf stride (f32): %4==0 (16B align), %8!=0 (bank spread)

typedef _Float16 half8  __attribute__((ext_vector_type(8)));
typedef _Float16 half4  __attribute__((ext_vector_type(4)));
typedef float    floatx4 __attribute__((ext_vector_type(4)));

__device__ __forceinline__ float sigf(float x) {
    // 1/(1+e^-x); v_exp + v_rcp. Saturates correctly at +-inf.
    return __builtin_amdgcn_rcpf(1.0f + __expf(-x));
}
__device__ __forceinline__ float tanhfast(float x) {
    // 1 - 2/(1+e^{2x}); exact at 0, saturates to +-1.
    return 1.0f - 2.0f * __builtin_amdgcn_rcpf(1.0f + __expf(2.0f * x));
}

// B-fragment loader for layers 1/2: panel k: [0,64)=Wih cols, [64,128)=Whh cols
__device__ __forceinline__ half8 ldfrag_l12(const float* Wih, const float* Whh,
                                            int n, int s) {
    const float* src = (s < HH) ? (Wih + n * HH + s) : (Whh + n * HH + (s - HH));
    half8 r;
#pragma unroll
    for (int j = 0; j < 8; ++j) r[j] = (_Float16)src[j];
    return r;
}

// B-fragment loader for layer 0 (enc kih=8, dec kih=72):
// panel k: [0,8)=Wih x-cols, [8,32)=zeros, [32,96)=Whh, [96,160)=Wih y-cols(8..71)
__device__ __forceinline__ half8 ldfrag_l0(const float* Wih, int kih,
                                           const float* Whh, int n, int s) {
    half8 r;
    const float* src = nullptr;
    if (s < 8)        src = Wih + n * kih + s;
    else if (s < 32)  src = nullptr;
    else if (s < 96)  src = Whh + n * HH + (s - 32);
    else              src = Wih + n * kih + (s - 88);
    if (src) {
#pragma unroll
        for (int j = 0; j < 8; ++j) r[j] = (_Float16)src[j];
    } else {
#pragma unroll
        for (int j = 0; j < 8; ++j) r[j] = (_Float16)0.f;
    }
    return r;
}

// One layer's gate GEMM: acc(bias-init) += A(panel) * Wf; scatter preacts to gbuf.
template <int KT, int KW>
__device__ __forceinline__ void gemm_layer(const _Float16* panel, int stride,
                                           const half8 (&wf)[KW][2],
                                           const float (&br)[2], float* gb,
                                           int l15, int q, int nbase) {
    floatx4 acc[2][2];
#pragma unroll
    for (int mt = 0; mt < 2; ++mt)
#pragma unroll
        for (int nt = 0; nt < 2; ++nt)
            acc[mt][nt] = (floatx4){br[nt], br[nt], br[nt], br[nt]};
#pragma unroll
    for (int kt = 0; kt < KT; ++kt) {
        const _Float16* pk = panel + kt * 32 + q * 8;
        half8 a0 = *(const half8*)(pk + l15 * stride);
        half8 a1 = *(const half8*)(pk + (16 + l15) * stride);
        acc[0][0] = __builtin_amdgcn_mfma_f32_16x16x32_f16(a0, wf[kt][0], acc[0][0], 0, 0, 0);
        acc[0][1] = __builtin_amdgcn_mfma_f32_16x16x32_f16(a0, wf[kt][1], acc[0][1], 0, 0, 0);
        acc[1][0] = __builtin_amdgcn_mfma_f32_16x16x32_f16(a1, wf[kt][0], acc[1][0], 0, 0, 0);
        acc[1][1] = __builtin_amdgcn_mfma_f32_16x16x32_f16(a1, wf[kt][1], acc[1][1], 0, 0, 0);
    }
    // C/D layout: col=lane&15, row=(lane>>4)*4+reg  [HW-verified mapping]
#pragma unroll
    for (int mt = 0; mt < 2; ++mt)
#pragma unroll
        for (int nt = 0; nt < 2; ++nt) {
            const int n = nbase + nt * 16 + l15;
#pragma unroll
            for (int r = 0; r < 4; ++r)
                gb[(mt * 16 + q * 4 + r) * NP + n] = acc[mt][nt][r];
        }
}

// Elementwise LSTM cell update for this thread's 4 hidden units (one m-row).
__device__ __forceinline__ void ew_layer(const float* g, float (&c)[4],
                                         _Float16* h0dst, _Float16* h1dst) {
    floatx4 gi = *(const floatx4*)(g);
    floatx4 gf = *(const floatx4*)(g + 64);
    floatx4 gg = *(const floatx4*)(g + 128);
    floatx4 go = *(const floatx4*)(g + 192);
    half4 h4;
#pragma unroll
    for (int j = 0; j < 4; ++j) {
        float iv = sigf(gi[j]);
        float fv = sigf(gf[j]);
        float gv = tanhfast(gg[j]);
        float ov = sigf(go[j]);
        float cv = fv * c[j] + iv * gv;
        c[j] = cv;
        h4[j] = (_Float16)(ov * tanhfast(cv));
    }
    *(half4*)h0dst = h4;
    if (h1dst) *(half4*)h1dst = h4;
}

__global__ __launch_bounds__(512, 2) void seq2seq_kernel(
    const float* __restrict__ encx, const float* __restrict__ decx,
    const float* __restrict__ eW0i, const float* __restrict__ eW0h, const float* __restrict__ eb0,
    const float* __restrict__ eW1i, const float* __restrict__ eW1h, const float* __restrict__ eb1,
    const float* __restrict__ eW2i, const float* __restrict__ eW2h, const float* __restrict__ eb2,
    const float* __restrict__ dW0i, const float* __restrict__ dW0h, const float* __restrict__ db0,
    const float* __restrict__ dW1i, const float* __restrict__ dW1h, const float* __restrict__ db1,
    const float* __restrict__ dW2i, const float* __restrict__ dW2h, const float* __restrict__ db2,
    const float* __restrict__ fcW, const float* __restrict__ fcb,
    float* __restrict__ out) {
    __shared__ _Float16 p0[MM * S0];
    __shared__ _Float16 p1[MM * S12];
    __shared__ _Float16 p2[MM * S12];
    __shared__ float gbuf[MM * NP];

    const int tid  = threadIdx.x;
    const int lane = tid & 63;
    const int wave = tid >> 6;
    const int l15  = lane & 15;
    const int q    = lane >> 4;
    const int nbase = wave * 32;          // this wave's gate-column slice
    const int rbase = blockIdx.x * MM;    // batch rows [rbase, rbase+32)

    const int em = tid >> 4;              // elementwise row 0..31
    const int eu = (tid & 15) * 4;        // elementwise unit base 0..60

    for (int i = tid; i < MM * S0; i += 512)  p0[i] = (_Float16)0.f;
    for (int i = tid; i < MM * S12; i += 512) p1[i] = (_Float16)0.f;
    for (int i = tid; i < MM * S12; i += 512) p2[i] = (_Float16)0.f;

    float c0[4] = {0, 0, 0, 0}, c1[4] = {0, 0, 0, 0}, c2[4] = {0, 0, 0, 0};

    // ---------------- encoder weight fragments (registers) ----------------
    half8 w0[5][2], w1[4][2], w2[4][2];
    float b0r[2], b1r[2], b2r[2];
#pragma unroll
    for (int nt = 0; nt < 2; ++nt) {
        const int n = nbase + nt * 16 + l15;
#pragma unroll
        for (int kt = 0; kt < 3; ++kt) w0[kt][nt] = ldfrag_l0(eW0i, 8, eW0h, n, kt * 32 + q * 8);
#pragma unroll
        for (int kt = 0; kt < 4; ++kt) w1[kt][nt] = ldfrag_l12(eW1i, eW1h, n, kt * 32 + q * 8);
#pragma unroll
        for (int kt = 0; kt < 4; ++kt) w2[kt][nt] = ldfrag_l12(eW2i, eW2h, n, kt * 32 + q * 8);
        b0r[nt] = eb0[n]; b1r[nt] = eb1[n]; b2r[nt] = eb2[n];
    }

    const int xrow = tid >> 3;  // 0..31 (valid when tid<256)
    const int xcol = tid & 7;
    float xr = 0.f;
    if (tid < 256) xr = encx[(size_t)(rbase + xrow) * TT * DD + xcol];

    _Float16* h0w = p0 + em * S0 + 32 + eu;
    _Float16* x1w = p1 + em * S12 + eu;
    _Float16* h1w = p1 + em * S12 + 64 + eu;
    _Float16* x2w = p2 + em * S12 + eu;
    _Float16* h2w = p2 + em * S12 + 64 + eu;
    _Float16* yw  = p0 + em * S0 + 96 + eu;
    float* gme = gbuf + em * NP + eu;

    __syncthreads();

    // ---------------- encoder loop ----------------
    for (int t = 0; t < TT; ++t) {
        if (tid < 256) p0[xrow * S0 + xcol] = (_Float16)xr;
        __syncthreads();  // B0: x_t + prev-step h writes visible
        if (tid < 256 && t + 1 < TT)
            xr = encx[(size_t)(rbase + xrow) * TT * DD + (t + 1) * DD + xcol];
        gemm_layer<3>(p0, S0, w0, b0r, gbuf, l15, q, nbase);
        __syncthreads();  // B1: gates visible
        ew_layer(gme, c0, h0w, x1w);
        __syncthreads();  // B2: h0 visible
        gemm_layer<4>(p1, S12, w1, b1r, gbuf, l15, q, nbase);
        __syncthreads();  // B3
        ew_layer(gme, c1, h1w, x2w);
        __syncthreads();  // B4
        gemm_layer<4>(p2, S12, w2, b2r, gbuf, l15, q, nbase);
        __syncthreads();  // B5
        ew_layer(gme, c2, h2w, nullptr);
        // no barrier: next-iter B0 fences h2 before any reader (gemm2 @ t+1)
    }

    __syncthreads();

    // ---------------- decoder weight fragments ----------------
#pragma unroll
    for (int nt = 0; nt < 2; ++nt) {
        const int n = nbase + nt * 16 + l15;
#pragma unroll
        for (int kt = 0; kt < 5; ++kt) w0[kt][nt] = ldfrag_l0(dW0i, 72, dW0h, n, kt * 32 + q * 8);
#pragma unroll
        for (int kt = 0; kt < 4; ++kt) w1[kt][nt] = ldfrag_l12(dW1i, dW1h, n, kt * 32 + q * 8);
#pragma unroll
        for (int kt = 0; kt < 4; ++kt) w2[kt][nt] = ldfrag_l12(dW2i, dW2h, n, kt * 32 + q * 8);
        b0r[nt] = db0[n]; b1r[nt] = db1[n]; b2r[nt] = db2[n];
    }
    half8 fw[2];
    const float fbr = (l15 < 8) ? fcb[l15] : 0.f;
#pragma unroll
    for (int kt = 0; kt < 2; ++kt) {
        half8 r;
        if (l15 < 8) {
            const float* s = fcW + l15 * HH + kt * 32 + q * 8;
#pragma unroll
            for (int j = 0; j < 8; ++j) r[j] = (_Float16)s[j];
        } else {
#pragma unroll
            for (int j = 0; j < 8; ++j) r[j] = (_Float16)0.f;
        }
        fw[kt] = r;
    }

    // y_prev(=0) init; x-pad cols of p0 still zero from kernel init
    *(half4*)yw = (half4){(_Float16)0.f, (_Float16)0.f, (_Float16)0.f, (_Float16)0.f};
    if (tid < 256) xr = decx[(size_t)(rbase + xrow) * TT * DD + xcol];

    // ---------------- decoder loop ----------------
    for (int t = 0; t < TT; ++t) {
        if (tid < 256) p0[xrow * S0 + xcol] = (_Float16)xr;
        __syncthreads();  // B0
        if (tid < 256 && t + 1 < TT)
            xr = decx[(size_t)(rbase + xrow) * TT * DD + (t + 1) * DD + xcol];
        gemm_layer<5>(p0, S0, w0, b0r, gbuf, l15, q, nbase);
        __syncthreads();  // B1
        ew_layer(gme, c0, h0w, x1w);
        __syncthreads();  // B2
        gemm_layer<4>(p1, S12, w1, b1r, gbuf, l15, q, nbase);
        __syncthreads();  // B3
        ew_layer(gme, c1, h1w, x2w);
        __syncthreads();  // B4
        gemm_layer<4>(p2, S12, w2, b2r, gbuf, l15, q, nbase);
        __syncthreads();  // B5
        ew_layer(gme, c2, h2w, yw);   // h2 -> panel2 h-slot AND p0 y_prev slot
        __syncthreads();  // B6: h2 visible for FC
        if (wave == 0 || wave == 4) {
            const int mt = wave >> 2;  // wave0 -> rows 0..15, wave4 -> rows 16..31
            floatx4 fa = (floatx4){fbr, fbr, fbr, fbr};
#pragma unroll
            for (int kt = 0; kt < 2; ++kt) {
                half8 a = *(const half8*)(p2 + (mt * 16 + l15) * S12 + 64 + kt * 32 + q * 8);
                fa = __builtin_amdgcn_mfma_f32_16x16x32_f16(a, fw[kt], fa, 0, 0, 0);
            }
            if (l15 < 8) {
#pragma unroll
                for (int r = 0; r < 4; ++r)
                    out[(size_t)(rbase + mt * 16 + q * 4 + r) * TT * DD + (size_t)t * DD + l15] = fa[r];
            }
        }
        // FC reads fenced from next ew2-write by B0'..B5'; other waves wait at B0'
    }
}

extern "C" void kernel_launch(void* const* d_in, const int* in_sizes, int n_in,
                              void* d_out, int out_size, void* d_ws, size_t ws_size,
                              hipStream_t stream) {
    const float* encx = (const float*)d_in[0];
    const float* decx = (const float*)d_in[1];
    const float* eW0i = (const float*)d_in[2];
    const float* eW0h = (const float*)d_in[3];
    const float* eb0  = (const float*)d_in[4];
    const float* eW1i = (const float*)d_in[5];
    const float* eW1h = (const float*)d_in[6];
    const float* eb1  = (const float*)d_in[7];
    const float* eW2i = (const float*)d_in[8];
    const float* eW2h = (const float*)d_in[9];
    const float* eb2  = (const float*)d_in[10];
    const float* dW0i = (const float*)d_in[11];
    const float* dW0h = (const float*)d_in[12];
    const float* db0  = (const float*)d_in[13];
    const float* dW1i = (const float*)d_in[14];
    const float* dW1h = (const float*)d_in[15];
    const float* db1  = (const float*)d_in[16];
    const float* dW2i = (const float*)d_in[17];
    const float* dW2h = (const float*)d_in[18];
    const float* db2  = (const float*)d_in[19];
    const float* fcW  = (const float*)d_in[20];
    const float* fcb  = (const float*)d_in[21];
    float* out = (float*)d_out;

    seq2seq_kernel<<<dim3(256), dim3(512), 0, stream>>>(
        encx, decx, eW0i, eW0h, eb0, eW1i, eW1h, eb1, eW2i, eW2h, eb2,
        dW0i, dW0h, db0, dW1i, dW1h, db1, dW2i, dW2h, db2, fcW, fcb, out);
}